// Round 15
// baseline (620.626 us; speedup 1.0000x reference)
//
#include <hip/hip_runtime.h>

// BERT encoder block fwd. R15 = R14 + lsum zeroing folded into prep (memset
// graph node removed). Everything else R14 verbatim.
// Structure: prep -> qkvt(merged QK+VT) -> scores(+rowsum atomics) -> PV(/l)
// -> Wo -> LN1 -> FFN1(relu) -> FFN2 -> LN2. GEMM core: 256^2 4-phase template
// (T1 XCD swizzle, T2 LDS XOR swizzle, T3/T4 counted vmcnt, T5 setprio),
// LDS-staged coalesced epilogue.

typedef __attribute__((ext_vector_type(4))) float  f32x4;
typedef __attribute__((ext_vector_type(8))) short  s16x8;
typedef __attribute__((ext_vector_type(4))) short  s16x4;
typedef unsigned short u16;
typedef unsigned int   u32;

__device__ __forceinline__ float bf2f(short s) {
  u32 u = ((u32)(u16)s) << 16;
  float f; __builtin_memcpy(&f, &u, 4); return f;
}
__device__ __forceinline__ short f2bf(float f) {
  u32 u; __builtin_memcpy(&u, &f, 4);
  u32 r = (u + 0x7fffu + ((u >> 16) & 1u)) >> 16;   // RNE
  return (short)(u16)r;
}

__device__ __forceinline__ void gload16(const void* g, void* l) {
  __builtin_amdgcn_global_load_lds(
      (const __attribute__((address_space(1))) u32*)g,
      (__attribute__((address_space(3))) u32*)l, 16, 0, 0);
}

// stage one 128-row half of a 256x64 bf16 tile (2 gload16/thread, 512 threads)
__device__ __forceinline__ void stage_half(const char* gop, long long ldb,
                                           long long rowbase, int tt, int h,
                                           u16* ldsop, int tid) {
#pragma unroll
  for (int l = 0; l < 2; ++l) {
    const int o   = (l * 512 + tid) * 16;
    const int rih = o >> 7;
    const int scb = (o & 127) ^ ((rih & 7) << 4);
    gload16(gop + (rowbase + h * 128 + rih) * ldb + (long long)tt * 128 + scb,
            (char*)ldsop + h * 16384 + o);
  }
}

#define SABUF(c) (SMEM + (c) * 16384)
#define SBBUF(c) (SMEM + 32768 + (c) * 16384)

#define RD_A(MH) do { _Pragma("unroll") for (int mi = 0; mi < 4; ++mi) { \
    const int row_ = wm * 64 + (MH) * 128 + mi * 16 + lr; \
    const int sw_ = (row_ & 7) << 4; const int rb_ = row_ << 7; \
    _Pragma("unroll") for (int kk = 0; kk < 2; ++kk) \
      af[mi][kk] = *(const s16x8*)(pa + rb_ + (((kk << 6) | (kg << 4)) ^ sw_)); } } while (0)

#define RD_B(NH) do { _Pragma("unroll") for (int nj = 0; nj < 2; ++nj) { \
    const int row_ = wn * 32 + (NH) * 128 + nj * 16 + lr; \
    const int sw_ = (row_ & 7) << 4; const int rb_ = row_ << 7; \
    _Pragma("unroll") for (int kk = 0; kk < 2; ++kk) \
      bf[NH][nj][kk] = *(const s16x8*)(pb + rb_ + (((kk << 6) | (kg << 4)) ^ sw_)); } } while (0)

#define MM(MH, NH) do { _Pragma("unroll") for (int kk = 0; kk < 2; ++kk) \
    _Pragma("unroll") for (int mi = 0; mi < 4; ++mi) \
    _Pragma("unroll") for (int nj = 0; nj < 2; ++nj) \
      acc[(MH) * 4 + mi][(NH) * 2 + nj] = __builtin_amdgcn_mfma_f32_16x16x32_bf16( \
        af[mi][kk], bf[NH][nj][kk], acc[(MH) * 4 + mi][(NH) * 2 + nj], 0, 0, 0); } while (0)

#define PH_SYNC do { __builtin_amdgcn_s_barrier(); \
    asm volatile("s_waitcnt lgkmcnt(0)"); \
    __builtin_amdgcn_sched_barrier(0); } while (0)

// Epilogue MODE: 1 = +bias0[col]; 2 = relu(+bias0[col]); 3 = exp(scale*acc) +
//   row-sum atomics into lsum; 4 = acc / lsum[z*M+row]; 5 = +bias, route
//   col>>10 to two [*,1024] outputs spaced 16777216 elems (fused QK, b0/b1);
//   6 = +bias0[row] (V^T projection: rows are embedding dims).
template<int MODE>
__device__ __forceinline__ void gemm_body(
    int tl, int gx,
    const u16* __restrict__ A, const u16* __restrict__ BT, u16* __restrict__ C,
    const float* __restrict__ bias0, const float* __restrict__ bias1,
    float* __restrict__ lsum,
    int M, int N, int K, float scale,
    long long sA, long long sB, long long sC, u16* SMEM) {
  const int tilesPerZ = (M >> 8) * gx;
  const int bz = tl / tilesPerZ;
  const int rem = tl - bz * tilesPerZ;
  const long long bm = (long long)(rem / gx) * 256;
  const long long bn = (long long)(rem % gx) * 256;

  const char* Ag = (const char*)(A + (long long)bz * sA);
  const char* Bg = (const char*)(BT + (long long)bz * sB);
  u16* Cb = C + (long long)bz * sC;
  const long long ldb = (long long)K * 2;

  const int tid = threadIdx.x;
  const int lane = tid & 63, wid = tid >> 6;
  const int lr = lane & 15, kg = lane >> 4;
  const int wm = wid >> 2, wn = wid & 3;
  const int NT = K >> 6;

  f32x4 acc[8][4] = {};
  s16x8 af[4][2];
  s16x8 bf[2][2][2];

  // prologue: T0 fully + T1 first halves; wait T0 (4 loads may stay in flight)
  stage_half(Ag, ldb, bm, 0, 0, SABUF(0), tid);
  stage_half(Bg, ldb, bn, 0, 0, SBBUF(0), tid);
  stage_half(Ag, ldb, bm, 0, 1, SABUF(0), tid);
  stage_half(Bg, ldb, bn, 0, 1, SBBUF(0), tid);
  stage_half(Ag, ldb, bm, 1, 0, SABUF(1), tid);
  stage_half(Bg, ldb, bn, 1, 0, SBBUF(1), tid);
  asm volatile("s_waitcnt vmcnt(4)");
  __builtin_amdgcn_s_barrier();

  for (int T = 0; T < NT; ++T) {
    const int c = T & 1, cn = c ^ 1;
    const char* pa = (const char*)SABUF(c);
    const char* pb = (const char*)SBBUF(c);

    // phase 0: (mh0,nh0); stage (T+1).Ah1
    RD_A(0); RD_B(0);
    if (T + 1 < NT) stage_half(Ag, ldb, bm, T + 1, 1, SABUF(cn), tid);
    PH_SYNC;
    __builtin_amdgcn_s_setprio(1); MM(0, 0); __builtin_amdgcn_s_setprio(0);
    __builtin_amdgcn_s_barrier();

    // phase 1: (mh0,nh1); stage (T+1).Bh1
    RD_B(1);
    if (T + 1 < NT) stage_half(Bg, ldb, bn, T + 1, 1, SBBUF(cn), tid);
    PH_SYNC;
    __builtin_amdgcn_s_setprio(1); MM(0, 1); __builtin_amdgcn_s_setprio(0);
    __builtin_amdgcn_s_barrier();

    // phase 2: (mh1,nh0); stage (T+2).Ah0
    RD_A(1);
    if (T + 2 < NT) stage_half(Ag, ldb, bm, T + 2, 0, SABUF(c), tid);
    PH_SYNC;
    __builtin_amdgcn_s_setprio(1); MM(1, 0); __builtin_amdgcn_s_setprio(0);
    __builtin_amdgcn_s_barrier();

    // phase 3: (mh1,nh1); stage (T+2).Bh0; counted boundary wait
    if (T + 2 < NT) stage_half(Bg, ldb, bn, T + 2, 0, SBBUF(c), tid);
    PH_SYNC;
    __builtin_amdgcn_s_setprio(1); MM(1, 1); __builtin_amdgcn_s_setprio(0);
    if (T + 2 < NT)      { asm volatile("s_waitcnt vmcnt(4)"); }
    else if (T + 1 < NT) { asm volatile("s_waitcnt vmcnt(0)"); }
    __builtin_amdgcn_s_barrier();
  }

  // epilogue: acc -> LDS (swizzled conflict-free) -> coalesced 16B stores
  const long long zM = (long long)bz * M;
  u16* obase; long long ldc, bnl;
  const float* bptr = bias0;
  if (MODE == 5) {
    const int sel = (int)(bn >> 10);
    obase = C + (long long)sel * 16777216;
    ldc = 1024; bnl = bn & 1023;
    bptr = (sel == 0 ? bias0 : bias1);
  } else { obase = Cb; ldc = N; bnl = bn; }

#pragma unroll
  for (int nh = 0; nh < 2; ++nh)
#pragma unroll
    for (int nj = 0; nj < 2; ++nj) {
      const int col = wn * 32 + nh * 128 + nj * 16 + lr;
      float bv = 0.f;
      if (MODE == 1 || MODE == 2 || MODE == 5) bv = bptr[bnl + col];
#pragma unroll
      for (int mh = 0; mh < 2; ++mh)
#pragma unroll
        for (int mi = 0; mi < 4; ++mi) {
          const int row0 = wm * 64 + mh * 128 + mi * 16 + kg * 4;
#pragma unroll
          for (int r = 0; r < 4; ++r) {
            float v = acc[mh * 4 + mi][nh * 2 + nj][r];
            if (MODE == 1 || MODE == 2 || MODE == 5) v = v * scale + bv;
            if (MODE == 2) v = fmaxf(v, 0.f);
            if (MODE == 3) v = __expf(v * scale);
            if (MODE == 4) v = v / lsum[zM + bm + row0 + r];
            if (MODE == 6) v = v * scale + bias0[bm + row0 + r];
            SMEM[(row0 + r) * 256 + (col ^ (kg << 4))] = (u16)f2bf(v);
          }
        }
    }
  __syncthreads();
#pragma unroll
  for (int i = 0; i < 16; ++i) {
    const int o   = (i * 512 + tid) * 16;
    const int row = o >> 9;
    const int wb  = o & 511;
    const int gs  = (wb >> 4) ^ (((row >> 2) & 3) << 1);
    s16x8 d = *(const s16x8*)((const char*)SMEM + row * 512 + (gs << 4));
    if (MODE == 3) {
      float s = 0.f;
#pragma unroll
      for (int j = 0; j < 8; ++j) s += bf2f(d[j]);
#pragma unroll
      for (int off = 1; off < 32; off <<= 1) s += __shfl_xor(s, off);
      if ((lane & 31) == 0) atomicAdd(&lsum[zM + bm + row], s);
    }
    *(s16x8*)((char*)obase + (((long long)bm + row) * ldc + bnl) * 2 + wb) = d;
  }
}

// standalone wrapper: grid encodes (gx, gy, z); bijective XCD swizzle (m204)
template<int MODE>
__global__ __launch_bounds__(512, 2)
void gemm256(const u16* __restrict__ A, const u16* __restrict__ BT,
             u16* __restrict__ C,
             const float* __restrict__ bias0, const float* __restrict__ bias1,
             float* __restrict__ lsum,
             int M, int N, int K, float scale,
             long long sA, long long sB, long long sC) {
  __shared__ u16 SMEM[65536];
  const int gx = gridDim.x, gy = gridDim.y;
  const int nwg = gx * gy * gridDim.z;
  const int orig = (blockIdx.z * gy + blockIdx.y) * gx + blockIdx.x;
  const int q = nwg >> 3, r8 = nwg & 7;
  const int xcd = orig & 7, pos = orig >> 3;
  const int wg = (xcd < r8 ? xcd * (q + 1) : r8 * (q + 1) + (xcd - r8) * q) + pos;
  gemm_body<MODE>(wg, gx, A, BT, C, bias0, bias1, lsum,
                  M, N, K, scale, sA, sB, sC, SMEM);
}

// merged QK + VT: 768 blocks, jointly XCD-swizzled; wg<512 -> QK, else VT
__global__ __launch_bounds__(512, 2)
void qkvt(const u16* __restrict__ XB, const u16* __restrict__ WQKT,
          u16* __restrict__ Q, const float* __restrict__ bq,
          const float* __restrict__ bk,
          const u16* __restrict__ WVT, u16* __restrict__ VT,
          const float* __restrict__ bv) {
  __shared__ u16 SMEM[65536];
  const int orig = blockIdx.x;            // nwg = 768, q = 96, r8 = 0
  const int wg = (orig & 7) * 96 + (orig >> 3);
  if (wg < 512) {
    gemm_body<5>(wg, 8, XB, WQKT, Q, bq, bk, nullptr,
                 16384, 2048, 1024, 1.f, 0, 0, 0, SMEM);
  } else {
    gemm_body<6>(wg - 512, 8, WVT, XB, VT, bv, nullptr, nullptr,
                 1024, 2048, 1024, 1.f, 0, 2048LL * 1024, 1024LL * 2048, SMEM);
  }
}

// ---------------- prep: cast x->bf16 + 6 weight transposes + lsum zero
// bid: [0,16384) cast; [16384,20480) Wq/Wk/Wv/Wo; [20480,24576) W1;
// [24576,28672) W2; [28672,28688) zero lsum (16 blocks x 256 thr x 4 f32).
__global__ __launch_bounds__(256) void prep(
    const float* __restrict__ x,  u16* __restrict__ XB,
    const float* __restrict__ Wq, const float* __restrict__ Wk,
    const float* __restrict__ Wv, const float* __restrict__ Wo,
    const float* __restrict__ W1, const float* __restrict__ W2,
    u16* __restrict__ WQT, u16* __restrict__ WKT, u16* __restrict__ WVT,
    u16* __restrict__ WOT, u16* __restrict__ W1T, u16* __restrict__ W2T,
    float* __restrict__ lsum) {
  __shared__ float tile[32][33];
  const int bid = blockIdx.x;
  const int t = threadIdx.x;
  if (bid < 16384) {
    const long long i = (long long)bid * 256 + t;
    f32x4 v = ((const f32x4*)x)[i];
    s16x4 o;
#pragma unroll
    for (int j = 0; j < 4; j++) o[j] = f2bf(v[j]);
    ((s16x4*)XB)[i] = o;
    return;
  }
  if (bid >= 28672) {
    f32x4 z = {0.f, 0.f, 0.f, 0.f};
    ((f32x4*)lsum)[(bid - 28672) * 256 + t] = z;
    return;
  }
  const float* in; u16* out; int R, C, tb;
  if (bid < 20480) {
    const int w = (bid - 16384) >> 10;
    tb = (bid - 16384) & 1023;
    in  = (w == 0 ? Wq : w == 1 ? Wk : w == 2 ? Wv : Wo);
    out = (w == 0 ? WQT : w == 1 ? WKT : w == 2 ? WVT : WOT);
    R = 1024; C = 1024;
  } else if (bid < 24576) {
    tb = bid - 20480; in = W1; out = W1T; R = 1024; C = 4096;
  } else {
    tb = bid - 24576; in = W2; out = W2T; R = 4096; C = 1024;
  }
  const int tpr = C >> 5;
  const int r0 = (tb / tpr) * 32, c0 = (tb % tpr) * 32;
  const int tx = t & 31, ty = t >> 5;
#pragma unroll
  for (int i = 0; i < 32; i += 8)
    tile[ty + i][tx] = in[(long long)(r0 + ty + i) * C + (c0 + tx)];
  __syncthreads();
#pragma unroll
  for (int i = 0; i < 32; i += 8)
    out[(long long)(c0 + ty + i) * R + (r0 + tx)] = (u16)f2bf(tile[tx][ty + i]);
}

// ------------------------------------------- LN(a_bf16 + b_bf16) -> bf16 or f32
template<bool OUTF32>
__global__ __launch_bounds__(256) void ln_add(const u16* __restrict__ a,
                                              const u16* __restrict__ b,
                                              const float* __restrict__ g,
                                              const float* __restrict__ be,
                                              void* __restrict__ outp) {
  const long long row = blockIdx.x;
  const int t = threadIdx.x;
  s16x4 avv = ((const s16x4*)(a + row * 1024))[t];
  s16x4 bvv = ((const s16x4*)(b + row * 1024))[t];
  float v[4]; float sum = 0.f, ss = 0.f;
#pragma unroll
  for (int j = 0; j < 4; j++) { v[j] = bf2f(avv[j]) + bf2f(bvv[j]); sum += v[j]; ss += v[j] * v[j]; }
#pragma unroll
  for (int off = 32; off > 0; off >>= 1) { sum += __shfl_xor(sum, off); ss += __shfl_xor(ss, off); }
  __shared__ float red[8];
  if ((t & 63) == 0) { red[t >> 6] = sum; red[4 + (t >> 6)] = ss; }
  __syncthreads();
  sum = (red[0] + red[1]) + (red[2] + red[3]);
  ss  = (red[4] + red[5]) + (red[6] + red[7]);
  const float mu   = sum * (1.f / 1024.f);
  const float var  = ss * (1.f / 1024.f) - mu * mu;
  const float rstd = rsqrtf(var + 1e-5f);
  if (OUTF32) {
    f32x4 o;
#pragma unroll
    for (int j = 0; j < 4; j++) {
      const int c = t * 4 + j;
      o[j] = (v[j] - mu) * rstd * g[c] + be[c];
    }
    ((f32x4*)((float*)outp + row * 1024))[t] = o;
  } else {
    s16x4 o;
#pragma unroll
    for (int j = 0; j < 4; j++) {
      const int c = t * 4 + j;
      o[j] = f2bf((v[j] - mu) * rstd * g[c] + be[c]);
    }
    *(s16x4*)&((u16*)outp)[row * 1024 + t * 4] = o;
  }
}

// ---------------------------------------------------------------- launcher
extern "C" void kernel_launch(void* const* d_in, const int* in_sizes, int n_in,
                              void* d_out, int out_size, void* d_ws, size_t ws_size,
                              hipStream_t stream) {
  const float* x   = (const float*)d_in[0];
  const float* Wq  = (const float*)d_in[1];
  const float* bq  = (const float*)d_in[2];
  const float* Wk  = (const float*)d_in[3];
  const float* bk  = (const float*)d_in[4];
  const float* Wv  = (const float*)d_in[5];
  const float* bv  = (const float*)d_in[6];
  const float* Wo  = (const float*)d_in[7];
  const float* bo  = (const float*)d_in[8];
  const float* g1  = (const float*)d_in[9];
  const float* b1  = (const float*)d_in[10];
  const float* g2  = (const float*)d_in[11];
  const float* b2  = (const float*)d_in[12];
  const float* W1  = (const float*)d_in[13];
  const float* bf1 = (const float*)d_in[14];
  const float* W2  = (const float*)d_in[15];
  const float* bf2 = (const float*)d_in[16];
  float* out = (float*)d_out;

  // ws layout (bytes), liveness-checked aliasing (same as R13/R14):
  //  weights 0..25165824 (WQT/WKT contiguous for fused QK)
  //  XB 25165824 (32MiB) cast->LN1 | Q 58720256 | K 92274688 | lsum 125829120
  //  VT 159383552 | S 192937984 (64MiB): scores->PV, then AO2=S+0, H=S+32MiB,
  //  FFN=S+0. AO=Q after scores. HID=XB..V end (128MiB, dead by FFN1).
  char* ws = (char*)d_ws;
  u16* wsWQT = (u16*)(ws + 0);
  u16* wsWKT = (u16*)(ws + 2097152);
  u16* wsWVT = (u16*)(ws + 4194304);
  u16* wsWOT = (u16*)(ws + 6291456);
  u16* wsW1T = (u16*)(ws + 8388608);
  u16* wsW2T = (u16*)(ws + 16777216);
  u16* wsXB  = (u16*)(ws + 25165824);
  u16* wsQ   = (u16*)(ws + 58720256);
  u16* wsK   = (u16*)(ws + 92274688);
  u16* wsVT  = (u16*)(ws + 159383552);
  u16* wsS   = (u16*)(ws + 192937984);
  u16* wsAO  = wsQ;
  u16* wsAO2 = wsS;
  u16* wsH   = (u16*)(ws + 192937984 + 33554432);
  u16* wsHID = wsXB;
  u16* wsFFN = wsS;
  float* wsLSUM = (float*)(ws + 125829120);

  const float inv_sqrt_e = 0.03125f;   // 1/sqrt(1024)
  const float* nf = nullptr;
  float* nfm = nullptr;

  // 1) prep: cast + all weight transposes + lsum zero (one kernel)
  prep<<<28688, 256, 0, stream>>>(x, wsXB, Wq, Wk, Wv, Wo, W1, W2,
                                  wsWQT, wsWKT, wsWVT, wsWOT, wsW1T, wsW2T,
                                  wsLSUM);

  // 2) merged QK + VT (independent GEMMs, one 768-block dispatch)
  qkvt<<<768, 512, 0, stream>>>(wsXB, wsWQT, wsQ, bq, bk, wsWVT, wsVT, bv);

  // 3) P~ = exp(QK^T/32) + rowsum atomics into lsum
  gemm256<3><<<dim3(8, 8, 8), 512, 0, stream>>>(wsQ, wsK, wsS, nf, nf, wsLSUM,
                                                2048, 2048, 1024, inv_sqrt_e,
                                                2048LL * 1024, 2048LL * 1024, 2048LL * 2048);

  // 4) attn_out = (P~ V)/l -> AO (=Q region; Q dead after scores)
  gemm256<4><<<dim3(4, 8, 8), 512, 0, stream>>>(wsS, wsVT, wsAO, nf, nf, wsLSUM,
                                                2048, 1024, 2048, 1.f,
                                                2048LL * 2048, 1024LL * 2048, 2048LL * 1024);
  // 5) out-proj -> AO2 (=S region start; S dead after PV)
  gemm256<1><<<dim3(4, 64, 1), 512, 0, stream>>>(wsAO, wsWOT, wsAO2, bo, nf, nfm,
                                                 16384, 1024, 1024, 1.f, 0, 0, 0);

  // 6) h = LN(XB + AO2) -> H (S + 32MiB)
  ln_add<false><<<16384, 256, 0, stream>>>(wsXB, wsAO2, g1, b1, wsH);

  // 7) HID = relu(h W1 + bf1) -> HID (=XB..V, 128MiB, all dead by now)
  gemm256<2><<<dim3(16, 64, 1), 512, 0, stream>>>(wsH, wsW1T, wsHID, bf1, nf, nfm,
                                                  16384, 4096, 1024, 1.f, 0, 0, 0);

  // 8) FFN = HID W2 + bf2 -> FFN (=S start; AO2 dead after LN1)
  gemm256<1><<<dim3(4, 64, 1), 512, 0, stream>>>(wsHID, wsW2T, wsFFN, bf2, nf, nfm,
                                                 16384, 1024, 4096, 1.f, 0, 0, 0);

  // 9) out = LN(H + FFN), fp32
  ln_add<true><<<16384, 256, 0, stream>>>(wsH, wsFFN, g2, b2, out);

  (void)in_sizes; (void)n_in; (void)out_size; (void)ws_size;
}

// Round 16
// 600.517 us; speedup vs baseline: 1.0335x; 1.0335x over previous
//
#include <hip/hip_runtime.h>

// BERT encoder block fwd. R16 = R14 VERBATIM (best measured: 592us).
// R15's lsum-fold-into-prep regressed (likely lost memset/prep overlap in the
// graph + noise); reverted. Structure, locked: prep -> qkvt (merged QK+VT) ->
// scores(+rowsum atomics) -> PV(/l) -> Wo -> LN1 -> FFN1(relu) -> FFN2 -> LN2.
// GEMM core: 256^2 4-phase template (T1 XCD swizzle, T2 LDS XOR swizzle,
// T3/T4 counted vmcnt, T5 setprio), LDS-staged coalesced epilogue.

typedef __attribute__((ext_vector_type(4))) float  f32x4;
typedef __attribute__((ext_vector_type(8))) short  s16x8;
typedef __attribute__((ext_vector_type(4))) short  s16x4;
typedef unsigned short u16;
typedef unsigned int   u32;

__device__ __forceinline__ float bf2f(short s) {
  u32 u = ((u32)(u16)s) << 16;
  float f; __builtin_memcpy(&f, &u, 4); return f;
}
__device__ __forceinline__ short f2bf(float f) {
  u32 u; __builtin_memcpy(&u, &f, 4);
  u32 r = (u + 0x7fffu + ((u >> 16) & 1u)) >> 16;   // RNE
  return (short)(u16)r;
}

__device__ __forceinline__ void gload16(const void* g, void* l) {
  __builtin_amdgcn_global_load_lds(
      (const __attribute__((address_space(1))) u32*)g,
      (__attribute__((address_space(3))) u32*)l, 16, 0, 0);
}

// stage one 128-row half of a 256x64 bf16 tile (2 gload16/thread, 512 threads)
__device__ __forceinline__ void stage_half(const char* gop, long long ldb,
                                           long long rowbase, int tt, int h,
                                           u16* ldsop, int tid) {
#pragma unroll
  for (int l = 0; l < 2; ++l) {
    const int o   = (l * 512 + tid) * 16;
    const int rih = o >> 7;
    const int scb = (o & 127) ^ ((rih & 7) << 4);
    gload16(gop + (rowbase + h * 128 + rih) * ldb + (long long)tt * 128 + scb,
            (char*)ldsop + h * 16384 + o);
  }
}

#define SABUF(c) (SMEM + (c) * 16384)
#define SBBUF(c) (SMEM + 32768 + (c) * 16384)

#define RD_A(MH) do { _Pragma("unroll") for (int mi = 0; mi < 4; ++mi) { \
    const int row_ = wm * 64 + (MH) * 128 + mi * 16 + lr; \
    const int sw_ = (row_ & 7) << 4; const int rb_ = row_ << 7; \
    _Pragma("unroll") for (int kk = 0; kk < 2; ++kk) \
      af[mi][kk] = *(const s16x8*)(pa + rb_ + (((kk << 6) | (kg << 4)) ^ sw_)); } } while (0)

#define RD_B(NH) do { _Pragma("unroll") for (int nj = 0; nj < 2; ++nj) { \
    const int row_ = wn * 32 + (NH) * 128 + nj * 16 + lr; \
    const int sw_ = (row_ & 7) << 4; const int rb_ = row_ << 7; \
    _Pragma("unroll") for (int kk = 0; kk < 2; ++kk) \
      bf[NH][nj][kk] = *(const s16x8*)(pb + rb_ + (((kk << 6) | (kg << 4)) ^ sw_)); } } while (0)

#define MM(MH, NH) do { _Pragma("unroll") for (int kk = 0; kk < 2; ++kk) \
    _Pragma("unroll") for (int mi = 0; mi < 4; ++mi) \
    _Pragma("unroll") for (int nj = 0; nj < 2; ++nj) \
      acc[(MH) * 4 + mi][(NH) * 2 + nj] = __builtin_amdgcn_mfma_f32_16x16x32_bf16( \
        af[mi][kk], bf[NH][nj][kk], acc[(MH) * 4 + mi][(NH) * 2 + nj], 0, 0, 0); } while (0)

#define PH_SYNC do { __builtin_amdgcn_s_barrier(); \
    asm volatile("s_waitcnt lgkmcnt(0)"); \
    __builtin_amdgcn_sched_barrier(0); } while (0)

// Epilogue MODE: 1 = +bias0[col]; 2 = relu(+bias0[col]); 3 = exp(scale*acc) +
//   row-sum atomics into lsum; 4 = acc / lsum[z*M+row]; 5 = +bias, route
//   col>>10 to two [*,1024] outputs spaced 16777216 elems (fused QK, b0/b1);
//   6 = +bias0[row] (V^T projection: rows are embedding dims).
template<int MODE>
__device__ __forceinline__ void gemm_body(
    int tl, int gx,
    const u16* __restrict__ A, const u16* __restrict__ BT, u16* __restrict__ C,
    const float* __restrict__ bias0, const float* __restrict__ bias1,
    float* __restrict__ lsum,
    int M, int N, int K, float scale,
    long long sA, long long sB, long long sC, u16* SMEM) {
  const int tilesPerZ = (M >> 8) * gx;
  const int bz = tl / tilesPerZ;
  const int rem = tl - bz * tilesPerZ;
  const long long bm = (long long)(rem / gx) * 256;
  const long long bn = (long long)(rem % gx) * 256;

  const char* Ag = (const char*)(A + (long long)bz * sA);
  const char* Bg = (const char*)(BT + (long long)bz * sB);
  u16* Cb = C + (long long)bz * sC;
  const long long ldb = (long long)K * 2;

  const int tid = threadIdx.x;
  const int lane = tid & 63, wid = tid >> 6;
  const int lr = lane & 15, kg = lane >> 4;
  const int wm = wid >> 2, wn = wid & 3;
  const int NT = K >> 6;

  f32x4 acc[8][4] = {};
  s16x8 af[4][2];
  s16x8 bf[2][2][2];

  // prologue: T0 fully + T1 first halves; wait T0 (4 loads may stay in flight)
  stage_half(Ag, ldb, bm, 0, 0, SABUF(0), tid);
  stage_half(Bg, ldb, bn, 0, 0, SBBUF(0), tid);
  stage_half(Ag, ldb, bm, 0, 1, SABUF(0), tid);
  stage_half(Bg, ldb, bn, 0, 1, SBBUF(0), tid);
  stage_half(Ag, ldb, bm, 1, 0, SABUF(1), tid);
  stage_half(Bg, ldb, bn, 1, 0, SBBUF(1), tid);
  asm volatile("s_waitcnt vmcnt(4)");
  __builtin_amdgcn_s_barrier();

  for (int T = 0; T < NT; ++T) {
    const int c = T & 1, cn = c ^ 1;
    const char* pa = (const char*)SABUF(c);
    const char* pb = (const char*)SBBUF(c);

    // phase 0: (mh0,nh0); stage (T+1).Ah1
    RD_A(0); RD_B(0);
    if (T + 1 < NT) stage_half(Ag, ldb, bm, T + 1, 1, SABUF(cn), tid);
    PH_SYNC;
    __builtin_amdgcn_s_setprio(1); MM(0, 0); __builtin_amdgcn_s_setprio(0);
    __builtin_amdgcn_s_barrier();

    // phase 1: (mh0,nh1); stage (T+1).Bh1
    RD_B(1);
    if (T + 1 < NT) stage_half(Bg, ldb, bn, T + 1, 1, SBBUF(cn), tid);
    PH_SYNC;
    __builtin_amdgcn_s_setprio(1); MM(0, 1); __builtin_amdgcn_s_setprio(0);
    __builtin_amdgcn_s_barrier();

    // phase 2: (mh1,nh0); stage (T+2).Ah0
    RD_A(1);
    if (T + 2 < NT) stage_half(Ag, ldb, bm, T + 2, 0, SABUF(c), tid);
    PH_SYNC;
    __builtin_amdgcn_s_setprio(1); MM(1, 0); __builtin_amdgcn_s_setprio(0);
    __builtin_amdgcn_s_barrier();

    // phase 3: (mh1,nh1); stage (T+2).Bh0; counted boundary wait
    if (T + 2 < NT) stage_half(Bg, ldb, bn, T + 2, 0, SBBUF(c), tid);
    PH_SYNC;
    __builtin_amdgcn_s_setprio(1); MM(1, 1); __builtin_amdgcn_s_setprio(0);
    if (T + 2 < NT)      { asm volatile("s_waitcnt vmcnt(4)"); }
    else if (T + 1 < NT) { asm volatile("s_waitcnt vmcnt(0)"); }
    __builtin_amdgcn_s_barrier();
  }

  // epilogue: acc -> LDS (swizzled conflict-free) -> coalesced 16B stores
  const long long zM = (long long)bz * M;
  u16* obase; long long ldc, bnl;
  const float* bptr = bias0;
  if (MODE == 5) {
    const int sel = (int)(bn >> 10);
    obase = C + (long long)sel * 16777216;
    ldc = 1024; bnl = bn & 1023;
    bptr = (sel == 0 ? bias0 : bias1);
  } else { obase = Cb; ldc = N; bnl = bn; }

#pragma unroll
  for (int nh = 0; nh < 2; ++nh)
#pragma unroll
    for (int nj = 0; nj < 2; ++nj) {
      const int col = wn * 32 + nh * 128 + nj * 16 + lr;
      float bv = 0.f;
      if (MODE == 1 || MODE == 2 || MODE == 5) bv = bptr[bnl + col];
#pragma unroll
      for (int mh = 0; mh < 2; ++mh)
#pragma unroll
        for (int mi = 0; mi < 4; ++mi) {
          const int row0 = wm * 64 + mh * 128 + mi * 16 + kg * 4;
#pragma unroll
          for (int r = 0; r < 4; ++r) {
            float v = acc[mh * 4 + mi][nh * 2 + nj][r];
            if (MODE == 1 || MODE == 2 || MODE == 5) v = v * scale + bv;
            if (MODE == 2) v = fmaxf(v, 0.f);
            if (MODE == 3) v = __expf(v * scale);
            if (MODE == 4) v = v / lsum[zM + bm + row0 + r];
            if (MODE == 6) v = v * scale + bias0[bm + row0 + r];
            SMEM[(row0 + r) * 256 + (col ^ (kg << 4))] = (u16)f2bf(v);
          }
        }
    }
  __syncthreads();
#pragma unroll
  for (int i = 0; i < 16; ++i) {
    const int o   = (i * 512 + tid) * 16;
    const int row = o >> 9;
    const int wb  = o & 511;
    const int gs  = (wb >> 4) ^ (((row >> 2) & 3) << 1);
    s16x8 d = *(const s16x8*)((const char*)SMEM + row * 512 + (gs << 4));
    if (MODE == 3) {
      float s = 0.f;
#pragma unroll
      for (int j = 0; j < 8; ++j) s += bf2f(d[j]);
#pragma unroll
      for (int off = 1; off < 32; off <<= 1) s += __shfl_xor(s, off);
      if ((lane & 31) == 0) atomicAdd(&lsum[zM + bm + row], s);
    }
    *(s16x8*)((char*)obase + (((long long)bm + row) * ldc + bnl) * 2 + wb) = d;
  }
}

// standalone wrapper: grid encodes (gx, gy, z); bijective XCD swizzle (m204)
template<int MODE>
__global__ __launch_bounds__(512, 2)
void gemm256(const u16* __restrict__ A, const u16* __restrict__ BT,
             u16* __restrict__ C,
             const float* __restrict__ bias0, const float* __restrict__ bias1,
             float* __restrict__ lsum,
             int M, int N, int K, float scale,
             long long sA, long long sB, long long sC) {
  __shared__ u16 SMEM[65536];
  const int gx = gridDim.x, gy = gridDim.y;
  const int nwg = gx * gy * gridDim.z;
  const int orig = (blockIdx.z * gy + blockIdx.y) * gx + blockIdx.x;
  const int q = nwg >> 3, r8 = nwg & 7;
  const int xcd = orig & 7, pos = orig >> 3;
  const int wg = (xcd < r8 ? xcd * (q + 1) : r8 * (q + 1) + (xcd - r8) * q) + pos;
  gemm_body<MODE>(wg, gx, A, BT, C, bias0, bias1, lsum,
                  M, N, K, scale, sA, sB, sC, SMEM);
}

// merged QK + VT: 768 blocks, jointly XCD-swizzled; wg<512 -> QK, else VT
__global__ __launch_bounds__(512, 2)
void qkvt(const u16* __restrict__ XB, const u16* __restrict__ WQKT,
          u16* __restrict__ Q, const float* __restrict__ bq,
          const float* __restrict__ bk,
          const u16* __restrict__ WVT, u16* __restrict__ VT,
          const float* __restrict__ bv) {
  __shared__ u16 SMEM[65536];
  const int orig = blockIdx.x;            // nwg = 768, q = 96, r8 = 0
  const int wg = (orig & 7) * 96 + (orig >> 3);
  if (wg < 512) {
    gemm_body<5>(wg, 8, XB, WQKT, Q, bq, bk, nullptr,
                 16384, 2048, 1024, 1.f, 0, 0, 0, SMEM);
  } else {
    gemm_body<6>(wg - 512, 8, WVT, XB, VT, bv, nullptr, nullptr,
                 1024, 2048, 1024, 1.f, 0, 2048LL * 1024, 1024LL * 2048, SMEM);
  }
}

// ------------------------------------------- prep: cast x->bf16 + 6 weight transposes
__global__ __launch_bounds__(256) void prep(
    const float* __restrict__ x,  u16* __restrict__ XB,
    const float* __restrict__ Wq, const float* __restrict__ Wk,
    const float* __restrict__ Wv, const float* __restrict__ Wo,
    const float* __restrict__ W1, const float* __restrict__ W2,
    u16* __restrict__ WQT, u16* __restrict__ WKT, u16* __restrict__ WVT,
    u16* __restrict__ WOT, u16* __restrict__ W1T, u16* __restrict__ W2T) {
  __shared__ float tile[32][33];
  const int bid = blockIdx.x;
  const int t = threadIdx.x;
  if (bid < 16384) {
    const long long i = (long long)bid * 256 + t;
    f32x4 v = ((const f32x4*)x)[i];
    s16x4 o;
#pragma unroll
    for (int j = 0; j < 4; j++) o[j] = f2bf(v[j]);
    ((s16x4*)XB)[i] = o;
    return;
  }
  const float* in; u16* out; int R, C, tb;
  if (bid < 20480) {
    const int w = (bid - 16384) >> 10;
    tb = (bid - 16384) & 1023;
    in  = (w == 0 ? Wq : w == 1 ? Wk : w == 2 ? Wv : Wo);
    out = (w == 0 ? WQT : w == 1 ? WKT : w == 2 ? WVT : WOT);
    R = 1024; C = 1024;
  } else if (bid < 24576) {
    tb = bid - 20480; in = W1; out = W1T; R = 1024; C = 4096;
  } else {
    tb = bid - 24576; in = W2; out = W2T; R = 4096; C = 1024;
  }
  const int tpr = C >> 5;
  const int r0 = (tb / tpr) * 32, c0 = (tb % tpr) * 32;
  const int tx = t & 31, ty = t >> 5;
#pragma unroll
  for (int i = 0; i < 32; i += 8)
    tile[ty + i][tx] = in[(long long)(r0 + ty + i) * C + (c0 + tx)];
  __syncthreads();
#pragma unroll
  for (int i = 0; i < 32; i += 8)
    out[(long long)(c0 + ty + i) * R + (r0 + tx)] = (u16)f2bf(tile[tx][ty + i]);
}

// ------------------------------------------- LN(a_bf16 + b_bf16) -> bf16 or f32
template<bool OUTF32>
__global__ __launch_bounds__(256) void ln_add(const u16* __restrict__ a,
                                              const u16* __restrict__ b,
                                              const float* __restrict__ g,
                                              const float* __restrict__ be,
                                              void* __restrict__ outp) {
  const long long row = blockIdx.x;
  const int t = threadIdx.x;
  s16x4 avv = ((const s16x4*)(a + row * 1024))[t];
  s16x4 bvv = ((const s16x4*)(b + row * 1024))[t];
  float v[4]; float sum = 0.f, ss = 0.f;
#pragma unroll
  for (int j = 0; j < 4; j++) { v[j] = bf2f(avv[j]) + bf2f(bvv[j]); sum += v[j]; ss += v[j] * v[j]; }
#pragma unroll
  for (int off = 32; off > 0; off >>= 1) { sum += __shfl_xor(sum, off); ss += __shfl_xor(ss, off); }
  __shared__ float red[8];
  if ((t & 63) == 0) { red[t >> 6] = sum; red[4 + (t >> 6)] = ss; }
  __syncthreads();
  sum = (red[0] + red[1]) + (red[2] + red[3]);
  ss  = (red[4] + red[5]) + (red[6] + red[7]);
  const float mu   = sum * (1.f / 1024.f);
  const float var  = ss * (1.f / 1024.f) - mu * mu;
  const float rstd = rsqrtf(var + 1e-5f);
  if (OUTF32) {
    f32x4 o;
#pragma unroll
    for (int j = 0; j < 4; j++) {
      const int c = t * 4 + j;
      o[j] = (v[j] - mu) * rstd * g[c] + be[c];
    }
    ((f32x4*)((float*)outp + row * 1024))[t] = o;
  } else {
    s16x4 o;
#pragma unroll
    for (int j = 0; j < 4; j++) {
      const int c = t * 4 + j;
      o[j] = f2bf((v[j] - mu) * rstd * g[c] + be[c]);
    }
    *(s16x4*)&((u16*)outp)[row * 1024 + t * 4] = o;
  }
}

// ---------------------------------------------------------------- launcher
extern "C" void kernel_launch(void* const* d_in, const int* in_sizes, int n_in,
                              void* d_out, int out_size, void* d_ws, size_t ws_size,
                              hipStream_t stream) {
  const float* x   = (const float*)d_in[0];
  const float* Wq  = (const float*)d_in[1];
  const float* bq  = (const float*)d_in[2];
  const float* Wk  = (const float*)d_in[3];
  const float* bk  = (const float*)d_in[4];
  const float* Wv  = (const float*)d_in[5];
  const float* bv  = (const float*)d_in[6];
  const float* Wo  = (const float*)d_in[7];
  const float* bo  = (const float*)d_in[8];
  const float* g1  = (const float*)d_in[9];
  const float* b1  = (const float*)d_in[10];
  const float* g2  = (const float*)d_in[11];
  const float* b2  = (const float*)d_in[12];
  const float* W1  = (const float*)d_in[13];
  const float* bf1 = (const float*)d_in[14];
  const float* W2  = (const float*)d_in[15];
  const float* bf2 = (const float*)d_in[16];
  float* out = (float*)d_out;

  // ws layout (bytes), liveness-checked aliasing:
  //  weights 0..25165824 (WQT/WKT contiguous for fused QK)
  //  XB 25165824 (32MiB) cast->LN1 | Q 58720256 | K 92274688 | lsum 125829120
  //  VT 159383552 | S 192937984 (64MiB): scores->PV, then AO2=S+0, H=S+32MiB,
  //  FFN=S+0. AO=Q after scores. HID=XB..V end (128MiB, dead by FFN1).
  char* ws = (char*)d_ws;
  u16* wsWQT = (u16*)(ws + 0);
  u16* wsWKT = (u16*)(ws + 2097152);
  u16* wsWVT = (u16*)(ws + 4194304);
  u16* wsWOT = (u16*)(ws + 6291456);
  u16* wsW1T = (u16*)(ws + 8388608);
  u16* wsW2T = (u16*)(ws + 16777216);
  u16* wsXB  = (u16*)(ws + 25165824);
  u16* wsQ   = (u16*)(ws + 58720256);
  u16* wsK   = (u16*)(ws + 92274688);
  u16* wsVT  = (u16*)(ws + 159383552);
  u16* wsS   = (u16*)(ws + 192937984);
  u16* wsAO  = wsQ;
  u16* wsAO2 = wsS;
  u16* wsH   = (u16*)(ws + 192937984 + 33554432);
  u16* wsHID = wsXB;
  u16* wsFFN = wsS;
  float* wsLSUM = (float*)(ws + 125829120);

  const float inv_sqrt_e = 0.03125f;   // 1/sqrt(1024)
  const float* nf = nullptr;
  float* nfm = nullptr;

  // 1) prep: cast x->bf16 + all weight transposes; zero lsum (independent node)
  prep<<<28672, 256, 0, stream>>>(x, wsXB, Wq, Wk, Wv, Wo, W1, W2,
                                  wsWQT, wsWKT, wsWVT, wsWOT, wsW1T, wsW2T);
  hipMemsetAsync(wsLSUM, 0, 16384 * sizeof(float), stream);

  // 2) merged QK + VT (independent GEMMs, one 768-block dispatch)
  qkvt<<<768, 512, 0, stream>>>(wsXB, wsWQT, wsQ, bq, bk, wsWVT, wsVT, bv);

  // 3) P~ = exp(QK^T/32) + rowsum atomics into lsum
  gemm256<3><<<dim3(8, 8, 8), 512, 0, stream>>>(wsQ, wsK, wsS, nf, nf, wsLSUM,
                                                2048, 2048, 1024, inv_sqrt_e,
                                                2048LL * 1024, 2048LL * 1024, 2048LL * 2048);

  // 4) attn_out = (P~ V)/l -> AO (=Q region; Q dead after scores)
  gemm256<4><<<dim3(4, 8, 8), 512, 0, stream>>>(wsS, wsVT, wsAO, nf, nf, wsLSUM,
                                                2048, 1024, 2048, 1.f,
                                                2048LL * 2048, 1024LL * 2048, 2048LL * 1024);
  // 5) out-proj -> AO2 (=S region start; S dead after PV)
  gemm256<1><<<dim3(4, 64, 1), 512, 0, stream>>>(wsAO, wsWOT, wsAO2, bo, nf, nfm,
                                                 16384, 1024, 1024, 1.f, 0, 0, 0);

  // 6) h = LN(XB + AO2) -> H (S + 32MiB)
  ln_add<false><<<16384, 256, 0, stream>>>(wsXB, wsAO2, g1, b1, wsH);

  // 7) HID = relu(h W1 + bf1) -> HID (=XB..V, 128MiB, all dead by now)
  gemm256<2><<<dim3(16, 64, 1), 512, 0, stream>>>(wsH, wsW1T, wsHID, bf1, nf, nfm,
                                                  16384, 4096, 1024, 1.f, 0, 0, 0);

  // 8) FFN = HID W2 + bf2 -> FFN (=S start; AO2 dead after LN1)
  gemm256<1><<<dim3(4, 64, 1), 512, 0, stream>>>(wsHID, wsW2T, wsFFN, bf2, nf, nfm,
                                                 16384, 1024, 4096, 1.f, 0, 0, 0);

  // 9) out = LN(H + FFN), fp32
  ln_add<true><<<16384, 256, 0, stream>>>(wsH, wsFFN, g2, b2, out);

  (void)in_sizes; (void)n_in; (void)out_size; (void)ws_size;
}